// Round 12
// baseline (2369.774 us; speedup 1.0000x reference)
//
#include <hip/hip_runtime.h>
#include <cstddef>

#define NB 32
#define NT 512
#define ND 1024
#define NH 1024
#define NG 4096   // 4*NH
#define GRID 256  // 8 groups (blockIdx&7, 4 batch rows) x 32 slots (32 units)

typedef unsigned short ushortT;
typedef __attribute__((ext_vector_type(8))) short short8;   // 8 bf16 = 4 VGPR
typedef __attribute__((ext_vector_type(4))) float f32x4;
typedef __attribute__((ext_vector_type(4))) unsigned uint4v;

#define GLL16(g, l) __builtin_amdgcn_global_load_lds(                      \
    (const __attribute__((address_space(1))) void*)(g),                    \
    (__attribute__((address_space(3))) void*)(l), 16, 0, 0)

__device__ __forceinline__ ushortT f2bf(float f) {
    union { float f; unsigned u; } v; v.f = f;
    unsigned r = v.u + 0x7FFFu + ((v.u >> 16) & 1u);   // RNE
    return (ushortT)(r >> 16);
}
__device__ __forceinline__ float bf2f(ushortT u) {
    union { unsigned u; float f; } v; v.u = (unsigned)u << 16; return v.f;
}

__device__ __forceinline__ float pick4(float a0, float a1, float a2, float a3, int s) {
    float lo = (s & 1) ? a1 : a0;
    float hi = (s & 1) ? a3 : a2;
    return (s & 2) ? hi : lo;
}

__device__ __forceinline__ float fsigmoid(float x) {
    return __builtin_amdgcn_rcpf(1.f + __expf(-x));
}
__device__ __forceinline__ float ftanh(float x) {
    float xc = fminf(fmaxf(x, -15.f), 15.f);
    float e  = __expf(-2.f * xc);
    return (1.f - e) * __builtin_amdgcn_rcpf(1.f + e);
}

// ---------------------------------------------------------------------------
__global__ __launch_bounds__(256) void cast_bf16(const float* __restrict__ src,
                                                 ushortT* __restrict__ dst, int n4)
{
    int i = blockIdx.x * 256 + threadIdx.x;
    if (i < n4) {
        float4 v = ((const float4*)src)[i];
        ushort4 o;
        o.x = f2bf(v.x); o.y = f2bf(v.y); o.z = f2bf(v.z); o.w = f2bf(v.w);
        ((ushort4*)dst)[i] = o;
    }
}

// ---------------------------------------------------------------------------
// transpose + cast: src f32 [1024][4096] -> dst bf16 [4096][1024]
// permute=1 remaps dst row n=(g*1024+j) -> (j>>2)*16 + g*4 + (j&3)
// ---------------------------------------------------------------------------
__global__ __launch_bounds__(256) void transpose_cast(
    const float* __restrict__ src, ushortT* __restrict__ dst, int permute)
{
    __shared__ ushortT tile[64][66];
    const int c0 = blockIdx.x * 64, r0 = blockIdx.y * 64;
    const int cc = threadIdx.x & 63, rq = threadIdx.x >> 6;
    #pragma unroll
    for (int ps = 0; ps < 16; ++ps) {
        int r = ps * 4 + rq;
        tile[cc][r] = f2bf(src[(size_t)(r0 + r) * NG + c0 + cc]);
    }
    __syncthreads();
    #pragma unroll
    for (int ps = 0; ps < 16; ++ps) {
        int cl = ps * 4 + rq;
        int n  = c0 + cl;
        int drow = permute ? ((((n & 1023) >> 2) << 4) | ((n >> 10) << 2) | (n & 3))
                           : n;
        dst[(size_t)drow * 1024 + r0 + cc] = tile[cl][cc];
    }
}

// ---------------------------------------------------------------------------
// xW GEMM, bf16 MFMA, global_load_lds staging (unchanged, proven r7-r9).
// Epilogue: bf16 + permuted cols:  xwpb[(trel*NB+b)][perm(n)]
// ---------------------------------------------------------------------------
__global__ __launch_bounds__(256) void gemm_xw_mfma(
    const ushortT* __restrict__ xb,   // [NB*NT][ND] bf16
    const ushortT* __restrict__ wxT,  // [NG][ND]    bf16
    const float* __restrict__ bias,
    ushortT* __restrict__ XWPb,       // [Tc*NB][NG] bf16, permuted cols
    int t0, int Tc, int tcsh)
{
    __shared__ ushortT As[128 * 32];
    __shared__ ushortT Bs[128 * 32];

    const int tid  = threadIdx.x;
    const int lane = tid & 63;
    const int wv   = tid >> 6;
    const int wr   = wv >> 1, wc = wv & 1;
    const int n0   = blockIdx.x * 128;
    const int m0   = blockIdx.y * 128;

    const int c1 = tid, c2 = tid + 256;
    const int rm1 = m0 + (c1 >> 2), rm2 = m0 + (c2 >> 2);
    const int xr1 = ((rm1 >> tcsh) * NT) + t0 + (rm1 & (Tc - 1));
    const int xr2 = ((rm2 >> tcsh) * NT) + t0 + (rm2 & (Tc - 1));
    const ushortT* ap1 = xb + (size_t)xr1 * ND + (c1 & 3) * 8;
    const ushortT* ap2 = xb + (size_t)xr2 * ND + (c2 & 3) * 8;
    const ushortT* bp1 = wxT + (size_t)(n0 + (c1 >> 2)) * ND + (c1 & 3) * 8;
    const ushortT* bp2 = wxT + (size_t)(n0 + (c2 >> 2)) * ND + (c2 & 3) * 8;

    f32x4 acc[4][4];
    #pragma unroll
    for (int m = 0; m < 4; ++m)
        #pragma unroll
        for (int n = 0; n < 4; ++n) acc[m][n] = (f32x4){0.f, 0.f, 0.f, 0.f};

    const int arow_base = (wr * 64 + (lane & 15)) * 32 + (lane >> 4) * 8;
    const int brow_base = (wc * 64 + (lane & 15)) * 32 + (lane >> 4) * 8;

    for (int k0 = 0; k0 < ND; k0 += 32) {
        __syncthreads();
        GLL16(ap1 + k0, &As[c1 * 8]);
        GLL16(ap2 + k0, &As[c2 * 8]);
        GLL16(bp1 + k0, &Bs[c1 * 8]);
        GLL16(bp2 + k0, &Bs[c2 * 8]);
        __syncthreads();
        short8 af[4], bf[4];
        #pragma unroll
        for (int m = 0; m < 4; ++m)
            af[m] = *(const short8*)&As[arow_base + m * 16 * 32];
        #pragma unroll
        for (int n = 0; n < 4; ++n)
            bf[n] = *(const short8*)&Bs[brow_base + n * 16 * 32];
        #pragma unroll
        for (int m = 0; m < 4; ++m)
            #pragma unroll
            for (int n = 0; n < 4; ++n)
                acc[m][n] = __builtin_amdgcn_mfma_f32_16x16x32_bf16(
                    af[m], bf[n], acc[m][n], 0, 0, 0);
    }

    #pragma unroll
    for (int n = 0; n < 4; ++n) {
        int col = n0 + wc * 64 + n * 16 + (lane & 15);
        int pc  = (((col & 1023) >> 2) << 4) | ((col >> 10) << 2) | (col & 3);
        float bs = bias[col];
        #pragma unroll
        for (int m = 0; m < 4; ++m) {
            #pragma unroll
            for (int r = 0; r < 4; ++r) {
                int rm = m0 + wr * 64 + m * 16 + (lane >> 4) * 4 + r;
                int b  = rm >> tcsh, tr = rm & (Tc - 1);
                XWPb[((size_t)tr * NB + b) * NG + pc] = f2bf(acc[m][n][r] + bs);
            }
        }
    }
}

// ---------------------------------------------------------------------------
// Persistent LSTM recurrence. AGENT-scope atomics ONLY (r9-proven protocol);
// no sc0, no XCD detection.
// grp = blockIdx&7 owns batch rows [4g,4g+4); sl = blockIdx>>3 owns hidden
// units [32sl,32sl+32) = permuted gate cols [128sl,128sl+128).
// 8 waves split K 8-way (units [128w,128w+128)); Wh register-resident
// (Bf[8][4] = 128 VGPR). A-frags loaded direct from h buffer via agent
// atomic loads (no LDS staging). M=16 MFMA with 4 real rows (lane&3 dup).
// Sync: per-BLOCK monotonic flag. Consumer wave w polls the 4 producer-block
// flags of its K-slice (union over 8 waves = whole group => h double-buffer
// overwrite safety, coupled by the per-step __syncthreads). Producer: h
// stores -> vmcnt(0) -> barrier -> tid0 publishes flag = trel+1.
// ---------------------------------------------------------------------------
__global__ __launch_bounds__(512) void lstm_persist(
    const ushortT* __restrict__ XWPb,  // [Tc*NB][NG] bf16, permuted cols
    const ushortT* __restrict__ whpT,  // [4096][1024] permuted bf16
    ushortT* __restrict__ hbuf,        // [2][NB][NH] bf16
    const float* __restrict__ cinit,
    float* __restrict__ cT,
    float* __restrict__ out,           // [NB][NT][NH] f32
    float* __restrict__ hT,
    unsigned* __restrict__ flags,      // [8][32], zeroed per launch
    int t0, int Tc)
{
    __shared__ float red[2][64][16][4];   // 32 KB: [par][w*8+ct][col16][row]

    const int tid  = threadIdx.x;
    const int lane = tid & 63;
    const int w    = tid >> 6;            // K-split wave
    const int grp  = blockIdx.x & 7;
    const int sl   = blockIdx.x >> 3;

    const int lo = lane & 15;
    const int hi = lane >> 4;

    // Wh register residency: block cols [128sl,+128), wave k-units [128w,+128)
    short8 Bf[8][4];
    #pragma unroll
    for (int ct = 0; ct < 8; ++ct)
        #pragma unroll
        for (int ks = 0; ks < 4; ++ks)
            Bf[ct][ks] = *(const short8*)(whpT
                + (size_t)(sl * 128 + ct * 16 + lo) * NH + w * 128 + ks * 32 + hi * 8);

    // activation roles: thread -> (row, col) of the 4x128 block outputs
    const int arow = tid >> 7;            // 0..3
    const int acol = tid & 127;           // permuted col within block
    const int gq   = (acol >> 2) & 3;
    const int u4   = (acol >> 4) * 4 + (acol & 3);   // unit 0..31
    const int brow = grp * 4 + arow;
    const int j    = sl * 32 + u4;

    float creg = cinit[(size_t)brow * NH + j];

    // A-frag source offset (shorts): 4 real rows duplicated over M=16
    const int aoff = (grp * 4 + (lane & 3)) * NH + w * 128 + hi * 8;

    unsigned* const fg = flags + grp * 32;
    // wave w consumes units [128w,+128) = blocks sl' = 4w..4w+3
    unsigned* const fpoll = fg + 4 * w + (lane & 3);
    unsigned* const fmine = fg + sl;

    ushortT xvr = XWPb[(size_t)brow * NG + sl * 128 + acol];

    const int tend = t0 + Tc;
    for (int t = t0; t < tend; ++t) {
        const int trel = t - t0;
        const int par  = t & 1;
        const ushortT* hRp = hbuf + (size_t)par * (NB * NH);
        ushortT*       hWp = hbuf + (size_t)(par ^ 1) * (NB * NH);

        // ---- wave-autonomous wait for this wave's 4 producer blocks ----
        if (trel) {
            const unsigned tgt = (unsigned)trel;
            for (int it = 0; it < (1 << 17); ++it) {
                unsigned v = __hip_atomic_load(fpoll, __ATOMIC_RELAXED,
                                               __HIP_MEMORY_SCOPE_AGENT);
                if (__all(v >= tgt)) break;
            }
        }

        // ---- A-fragments direct from h buffer (agent atomic 8B loads) ----
        const unsigned long long* sp = (const unsigned long long*)(hRp + aoff);
        unsigned long long p0, p1;
        uint4v Araw0, Araw1, Araw2, Araw3;
        p0 = __hip_atomic_load(sp + 0, __ATOMIC_RELAXED, __HIP_MEMORY_SCOPE_AGENT);
        p1 = __hip_atomic_load(sp + 1, __ATOMIC_RELAXED, __HIP_MEMORY_SCOPE_AGENT);
        Araw0 = (uint4v){(unsigned)p0, (unsigned)(p0 >> 32), (unsigned)p1, (unsigned)(p1 >> 32)};
        p0 = __hip_atomic_load(sp + 8, __ATOMIC_RELAXED, __HIP_MEMORY_SCOPE_AGENT);
        p1 = __hip_atomic_load(sp + 9, __ATOMIC_RELAXED, __HIP_MEMORY_SCOPE_AGENT);
        Araw1 = (uint4v){(unsigned)p0, (unsigned)(p0 >> 32), (unsigned)p1, (unsigned)(p1 >> 32)};
        p0 = __hip_atomic_load(sp + 16, __ATOMIC_RELAXED, __HIP_MEMORY_SCOPE_AGENT);
        p1 = __hip_atomic_load(sp + 17, __ATOMIC_RELAXED, __HIP_MEMORY_SCOPE_AGENT);
        Araw2 = (uint4v){(unsigned)p0, (unsigned)(p0 >> 32), (unsigned)p1, (unsigned)(p1 >> 32)};
        p0 = __hip_atomic_load(sp + 24, __ATOMIC_RELAXED, __HIP_MEMORY_SCOPE_AGENT);
        p1 = __hip_atomic_load(sp + 25, __ATOMIC_RELAXED, __HIP_MEMORY_SCOPE_AGENT);
        Araw3 = (uint4v){(unsigned)p0, (unsigned)(p0 >> 32), (unsigned)p1, (unsigned)(p1 >> 32)};

        short8 A0 = *(short8*)&Araw0;
        short8 A1 = *(short8*)&Araw1;
        short8 A2 = *(short8*)&Araw2;
        short8 A3 = *(short8*)&Araw3;

        // ---- 32 MFMAs: 8 independent chains of 4 ----
        #pragma unroll
        for (int ct = 0; ct < 8; ++ct) {
            f32x4 a = (f32x4){0.f, 0.f, 0.f, 0.f};
            a = __builtin_amdgcn_mfma_f32_16x16x32_bf16(A0, Bf[ct][0], a, 0, 0, 0);
            a = __builtin_amdgcn_mfma_f32_16x16x32_bf16(A1, Bf[ct][1], a, 0, 0, 0);
            a = __builtin_amdgcn_mfma_f32_16x16x32_bf16(A2, Bf[ct][2], a, 0, 0, 0);
            a = __builtin_amdgcn_mfma_f32_16x16x32_bf16(A3, Bf[ct][3], a, 0, 0, 0);
            if (hi == 0)
                *(f32x4*)&red[par][w * 8 + ct][lo][0] = a;
        }
        __syncthreads();   // SYNC1: red[par] writes visible

        // ---- reduce 8 K-splits + xW -> own-gate preact ----
        float g = bf2f(xvr);
        #pragma unroll
        for (int wv = 0; wv < 8; ++wv)
            g += red[par][wv * 8 + (acol >> 4)][acol & 15][arow];

        float g4  = __shfl_xor(g, 4);
        float g8  = __shfl_xor(g, 8);
        float g12 = __shfl_xor(g, 12);

        float gi = pick4(g, g4, g8, g12, gq);
        float gf = pick4(g, g4, g8, g12, gq ^ 1);
        float gg = pick4(g, g4, g8, g12, gq ^ 2);
        float go = pick4(g, g4, g8, g12, gq ^ 3);

        float iv = fsigmoid(gi);
        float fv = fsigmoid(gf);
        float gv = ftanh(gg);
        float ov = fsigmoid(go);
        float cn = fv * creg + iv * gv;
        float hn = ov * ftanh(cn);
        creg = cn;

        float ph = __shfl_xor(hn, 1);   // partner unit j^1
        const bool wl = (gq == 0) && ((acol & 1) == 0);
        unsigned pair = (unsigned)f2bf(hn) | ((unsigned)f2bf(ph) << 16);
        unsigned* hdst = (unsigned*)(hWp + (size_t)brow * NH + (j & ~1));
        if (wl)
            __hip_atomic_store(hdst, pair, __ATOMIC_RELAXED,
                               __HIP_MEMORY_SCOPE_AGENT);

        // SYNC2: drain h stores (all waves), also red read->write hazard
        asm volatile("s_waitcnt vmcnt(0)" ::: "memory");
        __syncthreads();

        if (t != tend - 1) {
            if (tid == 0)
                __hip_atomic_store(fmine, (unsigned)(trel + 1),
                                   __ATOMIC_RELAXED, __HIP_MEMORY_SCOPE_AGENT);
            // off-critical-path: out store + next-step xW prefetch
            if (wl)
                *(float2*)&out[((size_t)brow * NT + t) * NH + j] = make_float2(hn, ph);
            xvr = XWPb[((size_t)(trel + 1) * NB + brow) * NG + sl * 128 + acol];
        } else {
            if (wl)
                *(float2*)&out[((size_t)brow * NT + t) * NH + j] = make_float2(hn, ph);
            if (gq == 0) {
                if (t == NT - 1) hT[(size_t)brow * NH + j] = hn;
                cT[(size_t)brow * NH + j] = cn;
            }
        }
    }
}

// ---------------------------------------------------------------------------
extern "C" void kernel_launch(void* const* d_in, const int* in_sizes, int n_in,
                              void* d_out, int out_size, void* d_ws, size_t ws_size,
                              hipStream_t stream) {
    const float* x    = (const float*)d_in[0];
    const float* c0   = (const float*)d_in[1];
    const float* h0   = (const float*)d_in[2];
    const float* Wx   = (const float*)d_in[3];
    const float* Wh   = (const float*)d_in[4];
    const float* bias = (const float*)d_in[5];

    float* out = (float*)d_out;
    float* cT  = out + (size_t)NB * NT * NH;
    float* hT  = cT + (size_t)NB * NH;

    // ws: xb 33.5MB | wxT 8.4MB | whpT 8.4MB | hbuf 131KB | flags 1KB | xwpb
    ushortT* xb   = (ushortT*)d_ws;
    ushortT* wxT  = xb  + (size_t)NB * NT * ND;
    ushortT* whpT = wxT + (size_t)NG * ND;
    ushortT* hbuf = whpT + (size_t)NG * NH;
    unsigned* flags = (unsigned*)(hbuf + 2 * NB * NH);    // 8*32 dw
    ushortT* xwpb = (ushortT*)(flags + 8 * 32 + 32);      // pad

    const size_t fixed = ((size_t)NB * NT * ND + (size_t)NG * ND + (size_t)NG * NH
                          + 2 * NB * NH) * sizeof(ushortT)
                         + (8 * 32 + 32) * sizeof(unsigned) + 256;
    int Tc = 512;
    while (Tc > 4 && fixed + (size_t)NB * Tc * NG * sizeof(ushortT) > ws_size)
        Tc >>= 1;
    int tcsh = 31 - __builtin_clz(Tc);

    cast_bf16<<<(NB * NT * ND / 4 + 255) / 256, 256, 0, stream>>>(x, xb, NB * NT * ND / 4);
    // h0 -> hbuf parity 0
    cast_bf16<<<(NB * NH / 4 + 255) / 256, 256, 0, stream>>>(h0, hbuf, NB * NH / 4);
    transpose_cast<<<dim3(64, 16), 256, 0, stream>>>(Wx, wxT, 0);
    transpose_cast<<<dim3(64, 16), 256, 0, stream>>>(Wh, whpT, 1);

    for (int t0 = 0; t0 < NT; t0 += Tc) {
        dim3 g(NG / 128, (NB * Tc) / 128);
        gemm_xw_mfma<<<g, 256, 0, stream>>>(xb, wxT, bias, xwpb, t0, Tc, tcsh);
        hipMemsetAsync(flags, 0, (8 * 32) * sizeof(unsigned), stream);
        lstm_persist<<<GRID, 512, 0, stream>>>(
            xwpb, whpT, hbuf,
            (t0 == 0) ? c0 : (const float*)cT,
            cT, out, hT, flags, t0, Tc);
    }
}

// Round 13
// 2355.440 us; speedup vs baseline: 1.0061x; 1.0061x over previous
//
#include <hip/hip_runtime.h>
#include <cstddef>

#define NB 32
#define NT 512
#define ND 1024
#define NH 1024
#define NG 4096   // 4*NH
#define GRID 256  // 8 groups (blockIdx&7, 4 batch rows) x 32 slots (32 units)

typedef unsigned short ushortT;
typedef __attribute__((ext_vector_type(8))) short short8;   // 8 bf16 = 4 VGPR
typedef __attribute__((ext_vector_type(4))) float f32x4;
typedef __attribute__((ext_vector_type(4))) unsigned uint4v;

#define GLL16(g, l) __builtin_amdgcn_global_load_lds(                      \
    (const __attribute__((address_space(1))) void*)(g),                    \
    (__attribute__((address_space(3))) void*)(l), 16, 0, 0)

__device__ __forceinline__ ushortT f2bf(float f) {
    union { float f; unsigned u; } v; v.f = f;
    unsigned r = v.u + 0x7FFFu + ((v.u >> 16) & 1u);   // RNE
    return (ushortT)(r >> 16);
}
__device__ __forceinline__ float bf2f(ushortT u) {
    union { unsigned u; float f; } v; v.u = (unsigned)u << 16; return v.f;
}

__device__ __forceinline__ float pick4(float a0, float a1, float a2, float a3, int s) {
    float lo = (s & 1) ? a1 : a0;
    float hi = (s & 1) ? a3 : a2;
    return (s & 2) ? hi : lo;
}

__device__ __forceinline__ float fsigmoid(float x) {
    return __builtin_amdgcn_rcpf(1.f + __expf(-x));
}
__device__ __forceinline__ float ftanh(float x) {
    float xc = fminf(fmaxf(x, -15.f), 15.f);
    float e  = __expf(-2.f * xc);
    return (1.f - e) * __builtin_amdgcn_rcpf(1.f + e);
}

// ---------------------------------------------------------------------------
__global__ __launch_bounds__(256) void cast_bf16(const float* __restrict__ src,
                                                 ushortT* __restrict__ dst, int n4)
{
    int i = blockIdx.x * 256 + threadIdx.x;
    if (i < n4) {
        float4 v = ((const float4*)src)[i];
        ushort4 o;
        o.x = f2bf(v.x); o.y = f2bf(v.y); o.z = f2bf(v.z); o.w = f2bf(v.w);
        ((ushort4*)dst)[i] = o;
    }
}

// ---------------------------------------------------------------------------
// transpose + cast: src f32 [1024][4096] -> dst bf16 [4096][1024]
// permute=1 remaps dst row n=(g*1024+j) -> (j>>2)*16 + g*4 + (j&3)
// ---------------------------------------------------------------------------
__global__ __launch_bounds__(256) void transpose_cast(
    const float* __restrict__ src, ushortT* __restrict__ dst, int permute)
{
    __shared__ ushortT tile[64][66];
    const int c0 = blockIdx.x * 64, r0 = blockIdx.y * 64;
    const int cc = threadIdx.x & 63, rq = threadIdx.x >> 6;
    #pragma unroll
    for (int ps = 0; ps < 16; ++ps) {
        int r = ps * 4 + rq;
        tile[cc][r] = f2bf(src[(size_t)(r0 + r) * NG + c0 + cc]);
    }
    __syncthreads();
    #pragma unroll
    for (int ps = 0; ps < 16; ++ps) {
        int cl = ps * 4 + rq;
        int n  = c0 + cl;
        int drow = permute ? ((((n & 1023) >> 2) << 4) | ((n >> 10) << 2) | (n & 3))
                           : n;
        dst[(size_t)drow * 1024 + r0 + cc] = tile[cl][cc];
    }
}

// ---------------------------------------------------------------------------
// xW GEMM, bf16 MFMA, global_load_lds staging (proven r7-r12).
// Epilogue: bf16 + permuted cols:  xwpb[(trel*NB+b)][perm(n)]
// ---------------------------------------------------------------------------
__global__ __launch_bounds__(256) void gemm_xw_mfma(
    const ushortT* __restrict__ xb,   // [NB*NT][ND] bf16
    const ushortT* __restrict__ wxT,  // [NG][ND]    bf16
    const float* __restrict__ bias,
    ushortT* __restrict__ XWPb,       // [Tc*NB][NG] bf16, permuted cols
    int t0, int Tc, int tcsh)
{
    __shared__ ushortT As[128 * 32];
    __shared__ ushortT Bs[128 * 32];

    const int tid  = threadIdx.x;
    const int lane = tid & 63;
    const int wv   = tid >> 6;
    const int wr   = wv >> 1, wc = wv & 1;
    const int n0   = blockIdx.x * 128;
    const int m0   = blockIdx.y * 128;

    const int c1 = tid, c2 = tid + 256;
    const int rm1 = m0 + (c1 >> 2), rm2 = m0 + (c2 >> 2);
    const int xr1 = ((rm1 >> tcsh) * NT) + t0 + (rm1 & (Tc - 1));
    const int xr2 = ((rm2 >> tcsh) * NT) + t0 + (rm2 & (Tc - 1));
    const ushortT* ap1 = xb + (size_t)xr1 * ND + (c1 & 3) * 8;
    const ushortT* ap2 = xb + (size_t)xr2 * ND + (c2 & 3) * 8;
    const ushortT* bp1 = wxT + (size_t)(n0 + (c1 >> 2)) * ND + (c1 & 3) * 8;
    const ushortT* bp2 = wxT + (size_t)(n0 + (c2 >> 2)) * ND + (c2 & 3) * 8;

    f32x4 acc[4][4];
    #pragma unroll
    for (int m = 0; m < 4; ++m)
        #pragma unroll
        for (int n = 0; n < 4; ++n) acc[m][n] = (f32x4){0.f, 0.f, 0.f, 0.f};

    const int arow_base = (wr * 64 + (lane & 15)) * 32 + (lane >> 4) * 8;
    const int brow_base = (wc * 64 + (lane & 15)) * 32 + (lane >> 4) * 8;

    for (int k0 = 0; k0 < ND; k0 += 32) {
        __syncthreads();
        GLL16(ap1 + k0, &As[c1 * 8]);
        GLL16(ap2 + k0, &As[c2 * 8]);
        GLL16(bp1 + k0, &Bs[c1 * 8]);
        GLL16(bp2 + k0, &Bs[c2 * 8]);
        __syncthreads();
        short8 af[4], bf[4];
        #pragma unroll
        for (int m = 0; m < 4; ++m)
            af[m] = *(const short8*)&As[arow_base + m * 16 * 32];
        #pragma unroll
        for (int n = 0; n < 4; ++n)
            bf[n] = *(const short8*)&Bs[brow_base + n * 16 * 32];
        #pragma unroll
        for (int m = 0; m < 4; ++m)
            #pragma unroll
            for (int n = 0; n < 4; ++n)
                acc[m][n] = __builtin_amdgcn_mfma_f32_16x16x32_bf16(
                    af[m], bf[n], acc[m][n], 0, 0, 0);
    }

    #pragma unroll
    for (int n = 0; n < 4; ++n) {
        int col = n0 + wc * 64 + n * 16 + (lane & 15);
        int pc  = (((col & 1023) >> 2) << 4) | ((col >> 10) << 2) | (col & 3);
        float bs = bias[col];
        #pragma unroll
        for (int m = 0; m < 4; ++m) {
            #pragma unroll
            for (int r = 0; r < 4; ++r) {
                int rm = m0 + wr * 64 + m * 16 + (lane >> 4) * 4 + r;
                int b  = rm >> tcsh, tr = rm & (Tc - 1);
                XWPb[((size_t)tr * NB + b) * NG + pc] = f2bf(acc[m][n][r] + bs);
            }
        }
    }
}

// ---------------------------------------------------------------------------
// Persistent LSTM recurrence, r12-proven protocol + REPLICATED FLAGS.
// grp = blockIdx&7 owns batch rows [4g,4g+4); sl = blockIdx>>3 owns hidden
// units [32sl,32sl+32). 8 waves split K 8-way; Wh register-resident.
// Flags [grp][consumer][producer]: producer stores trel+1 into 32
// consumer-PRIVATE lines (wave0 lanes<32). Consumer: wave0 alone polls its
// own 128B flag row (1 reader/line), releases waves 1-7 via LDS token.
// Full-group coupling: flag=t  =>  that block finished READING h_{t-2},
// so overwriting buf[t&1] at step t is safe (classic 2-buffer argument).
// ---------------------------------------------------------------------------
__global__ __launch_bounds__(512) void lstm_persist(
    const ushortT* __restrict__ XWPb,  // [Tc*NB][NG] bf16, permuted cols
    const ushortT* __restrict__ whpT,  // [4096][1024] permuted bf16
    ushortT* __restrict__ hbuf,        // [2][NB][NH] bf16
    const float* __restrict__ cinit,
    float* __restrict__ cT,
    float* __restrict__ out,           // [NB][NT][NH] f32
    float* __restrict__ hT,
    unsigned* __restrict__ flags,      // [8][32][32], zeroed per launch
    int t0, int Tc)
{
    __shared__ float red[2][64][16][4];   // 32 KB: [par][w*8+ct][col16][row]
    __shared__ unsigned token;

    const int tid  = threadIdx.x;
    const int lane = tid & 63;
    const int w    = tid >> 6;            // K-split wave
    const int grp  = blockIdx.x & 7;
    const int sl   = blockIdx.x >> 3;

    const int lo = lane & 15;
    const int hi = lane >> 4;

    if (tid == 0) token = 0;

    // Wh register residency: block cols [128sl,+128), wave k-units [128w,+128)
    short8 Bf[8][4];
    #pragma unroll
    for (int ct = 0; ct < 8; ++ct)
        #pragma unroll
        for (int ks = 0; ks < 4; ++ks)
            Bf[ct][ks] = *(const short8*)(whpT
                + (size_t)(sl * 128 + ct * 16 + lo) * NH + w * 128 + ks * 32 + hi * 8);

    // activation roles: thread -> (row, col) of the 4x128 block outputs
    const int arow = tid >> 7;            // 0..3
    const int acol = tid & 127;           // permuted col within block
    const int gq   = (acol >> 2) & 3;
    const int u4   = (acol >> 4) * 4 + (acol & 3);   // unit 0..31
    const int brow = grp * 4 + arow;
    const int j    = sl * 32 + u4;

    float creg = cinit[(size_t)brow * NH + j];

    // A-frag source offset (shorts): 4 real rows duplicated over M=16
    const int aoff = (grp * 4 + (lane & 3)) * NH + w * 128 + hi * 8;

    unsigned* const fg = flags + grp * 1024;           // [32 consumer][32 producer]
    unsigned* const myrow = fg + sl * 32;              // this block's private row

    ushortT xvr = XWPb[(size_t)brow * NG + sl * 128 + acol];
    __syncthreads();   // token init visible

    const int tend = t0 + Tc;
    for (int t = t0; t < tend; ++t) {
        const int trel = t - t0;
        const int par  = t & 1;
        const ushortT* hRp = hbuf + (size_t)par * (NB * NH);
        ushortT*       hWp = hbuf + (size_t)(par ^ 1) * (NB * NH);

        // ---- wait: wave0 polls private flag row, LDS token releases rest ----
        if (trel) {
            const unsigned tgt = (unsigned)trel;
            if (w == 0) {
                unsigned* myf = myrow + (lane & 31);
                for (int it = 0; it < (1 << 17); ++it) {
                    unsigned v = __hip_atomic_load(myf, __ATOMIC_RELAXED,
                                                   __HIP_MEMORY_SCOPE_AGENT);
                    if (__all(v >= tgt)) break;
                }
                if (lane == 0)
                    __hip_atomic_store(&token, tgt, __ATOMIC_RELAXED,
                                       __HIP_MEMORY_SCOPE_WORKGROUP);
            } else {
                int it = 0;
                while (__hip_atomic_load(&token, __ATOMIC_RELAXED,
                                         __HIP_MEMORY_SCOPE_WORKGROUP) < tgt
                       && ++it < (1 << 22)) {}
            }
        }

        // ---- A-fragments direct from h buffer (agent atomic 8B loads) ----
        const unsigned long long* sp = (const unsigned long long*)(hRp + aoff);
        unsigned long long p0, p1;
        uint4v Araw0, Araw1, Araw2, Araw3;
        p0 = __hip_atomic_load(sp + 0, __ATOMIC_RELAXED, __HIP_MEMORY_SCOPE_AGENT);
        p1 = __hip_atomic_load(sp + 1, __ATOMIC_RELAXED, __HIP_MEMORY_SCOPE_AGENT);
        Araw0 = (uint4v){(unsigned)p0, (unsigned)(p0 >> 32), (unsigned)p1, (unsigned)(p1 >> 32)};
        p0 = __hip_atomic_load(sp + 8, __ATOMIC_RELAXED, __HIP_MEMORY_SCOPE_AGENT);
        p1 = __hip_atomic_load(sp + 9, __ATOMIC_RELAXED, __HIP_MEMORY_SCOPE_AGENT);
        Araw1 = (uint4v){(unsigned)p0, (unsigned)(p0 >> 32), (unsigned)p1, (unsigned)(p1 >> 32)};
        p0 = __hip_atomic_load(sp + 16, __ATOMIC_RELAXED, __HIP_MEMORY_SCOPE_AGENT);
        p1 = __hip_atomic_load(sp + 17, __ATOMIC_RELAXED, __HIP_MEMORY_SCOPE_AGENT);
        Araw2 = (uint4v){(unsigned)p0, (unsigned)(p0 >> 32), (unsigned)p1, (unsigned)(p1 >> 32)};
        p0 = __hip_atomic_load(sp + 24, __ATOMIC_RELAXED, __HIP_MEMORY_SCOPE_AGENT);
        p1 = __hip_atomic_load(sp + 25, __ATOMIC_RELAXED, __HIP_MEMORY_SCOPE_AGENT);
        Araw3 = (uint4v){(unsigned)p0, (unsigned)(p0 >> 32), (unsigned)p1, (unsigned)(p1 >> 32)};

        short8 A0 = *(short8*)&Araw0;
        short8 A1 = *(short8*)&Araw1;
        short8 A2 = *(short8*)&Araw2;
        short8 A3 = *(short8*)&Araw3;

        // ---- 32 MFMAs: 8 independent chains of 4 ----
        #pragma unroll
        for (int ct = 0; ct < 8; ++ct) {
            f32x4 a = (f32x4){0.f, 0.f, 0.f, 0.f};
            a = __builtin_amdgcn_mfma_f32_16x16x32_bf16(A0, Bf[ct][0], a, 0, 0, 0);
            a = __builtin_amdgcn_mfma_f32_16x16x32_bf16(A1, Bf[ct][1], a, 0, 0, 0);
            a = __builtin_amdgcn_mfma_f32_16x16x32_bf16(A2, Bf[ct][2], a, 0, 0, 0);
            a = __builtin_amdgcn_mfma_f32_16x16x32_bf16(A3, Bf[ct][3], a, 0, 0, 0);
            if (hi == 0)
                *(f32x4*)&red[par][w * 8 + ct][lo][0] = a;
        }
        __syncthreads();   // SYNC1: red[par] writes visible

        // ---- reduce 8 K-splits + xW -> own-gate preact ----
        float g = bf2f(xvr);
        #pragma unroll
        for (int wv = 0; wv < 8; ++wv)
            g += red[par][wv * 8 + (acol >> 4)][acol & 15][arow];

        float g4  = __shfl_xor(g, 4);
        float g8  = __shfl_xor(g, 8);
        float g12 = __shfl_xor(g, 12);

        float gi = pick4(g, g4, g8, g12, gq);
        float gf = pick4(g, g4, g8, g12, gq ^ 1);
        float gg = pick4(g, g4, g8, g12, gq ^ 2);
        float go = pick4(g, g4, g8, g12, gq ^ 3);

        float iv = fsigmoid(gi);
        float fv = fsigmoid(gf);
        float gv = ftanh(gg);
        float ov = fsigmoid(go);
        float cn = fv * creg + iv * gv;
        float hn = ov * ftanh(cn);
        creg = cn;

        float ph = __shfl_xor(hn, 1);   // partner unit j^1
        const bool wl = (gq == 0) && ((acol & 1) == 0);
        unsigned pair = (unsigned)f2bf(hn) | ((unsigned)f2bf(ph) << 16);
        unsigned* hdst = (unsigned*)(hWp + (size_t)brow * NH + (j & ~1));
        if (wl)
            __hip_atomic_store(hdst, pair, __ATOMIC_RELAXED,
                               __HIP_MEMORY_SCOPE_AGENT);

        // SYNC2: drain h stores (all waves), also red read->write hazard
        asm volatile("s_waitcnt vmcnt(0)" ::: "memory");
        __syncthreads();

        if (t != tend - 1) {
            // publish to 32 consumer-private lines (one wave-store)
            if (w == 0 && lane < 32)
                __hip_atomic_store(fg + lane * 32 + sl, (unsigned)(trel + 1),
                                   __ATOMIC_RELAXED, __HIP_MEMORY_SCOPE_AGENT);
            // off-critical-path: out store + next-step xW prefetch
            if (wl)
                *(float2*)&out[((size_t)brow * NT + t) * NH + j] = make_float2(hn, ph);
            xvr = XWPb[((size_t)(trel + 1) * NB + brow) * NG + sl * 128 + acol];
        } else {
            if (wl)
                *(float2*)&out[((size_t)brow * NT + t) * NH + j] = make_float2(hn, ph);
            if (gq == 0) {
                if (t == NT - 1) hT[(size_t)brow * NH + j] = hn;
                cT[(size_t)brow * NH + j] = cn;
            }
        }
    }
}

// ---------------------------------------------------------------------------
extern "C" void kernel_launch(void* const* d_in, const int* in_sizes, int n_in,
                              void* d_out, int out_size, void* d_ws, size_t ws_size,
                              hipStream_t stream) {
    const float* x    = (const float*)d_in[0];
    const float* c0   = (const float*)d_in[1];
    const float* h0   = (const float*)d_in[2];
    const float* Wx   = (const float*)d_in[3];
    const float* Wh   = (const float*)d_in[4];
    const float* bias = (const float*)d_in[5];

    float* out = (float*)d_out;
    float* cT  = out + (size_t)NB * NT * NH;
    float* hT  = cT + (size_t)NB * NH;

    // ws: xb 33.5MB | wxT 8.4MB | whpT 8.4MB | hbuf 131KB | flags 32KB | xwpb
    ushortT* xb   = (ushortT*)d_ws;
    ushortT* wxT  = xb  + (size_t)NB * NT * ND;
    ushortT* whpT = wxT + (size_t)NG * ND;
    ushortT* hbuf = whpT + (size_t)NG * NH;
    unsigned* flags = (unsigned*)(hbuf + 2 * NB * NH);    // 8*32*32 dw
    ushortT* xwpb = (ushortT*)(flags + 8 * 32 * 32 + 32); // pad

    const size_t fixed = ((size_t)NB * NT * ND + (size_t)NG * ND + (size_t)NG * NH
                          + 2 * NB * NH) * sizeof(ushortT)
                         + (8 * 32 * 32 + 32) * sizeof(unsigned) + 256;
    int Tc = 512;
    while (Tc > 4 && fixed + (size_t)NB * Tc * NG * sizeof(ushortT) > ws_size)
        Tc >>= 1;
    int tcsh = 31 - __builtin_clz(Tc);

    cast_bf16<<<(NB * NT * ND / 4 + 255) / 256, 256, 0, stream>>>(x, xb, NB * NT * ND / 4);
    // h0 -> hbuf parity 0
    cast_bf16<<<(NB * NH / 4 + 255) / 256, 256, 0, stream>>>(h0, hbuf, NB * NH / 4);
    transpose_cast<<<dim3(64, 16), 256, 0, stream>>>(Wx, wxT, 0);
    transpose_cast<<<dim3(64, 16), 256, 0, stream>>>(Wh, whpT, 1);

    for (int t0 = 0; t0 < NT; t0 += Tc) {
        dim3 g(NG / 128, (NB * Tc) / 128);
        gemm_xw_mfma<<<g, 256, 0, stream>>>(xb, wxT, bias, xwpb, t0, Tc, tcsh);
        hipMemsetAsync(flags, 0, (8 * 32 * 32) * sizeof(unsigned), stream);
        lstm_persist<<<GRID, 512, 0, stream>>>(
            xwpb, whpT, hbuf,
            (t0 == 0) ? c0 : (const float*)cT,
            cT, out, hT, flags, t0, Tc);
    }
}